// Round 17
// baseline (749.422 us; speedup 1.0000x reference)
//
#include <hip/hip_runtime.h>
#include <math.h>

#define SEQ    2048
#define EMBED  1280
#define HEADS  16
#define HD     80
#define MLP    5120
#define HIDDEN 3584
#define QKVN   3840
#define SEGLEN 1024
#define NSEG   2
#define PATCH_IN 1176
#define PATCH_KP 1280   // mult of 128
#define MROWS  512

typedef __attribute__((ext_vector_type(8))) short bf16x8;
typedef __attribute__((ext_vector_type(4))) short s16x4;
typedef __attribute__((ext_vector_type(4))) float f32x4;
typedef unsigned short ushort_t;

__device__ __forceinline__ ushort_t f2bf(float f) {
    unsigned u = __builtin_bit_cast(unsigned, f);
    unsigned r = u + 0x7FFFu + ((u >> 16) & 1u);   // RNE
    return (ushort_t)(r >> 16);
}

__device__ __forceinline__ float bf2f(ushort_t h) {
    unsigned u = (unsigned)h << 16;
    return __builtin_bit_cast(float, u);
}

__device__ __forceinline__ void gld_lds16(const void* g, void* l) {
    __builtin_amdgcn_global_load_lds(
        (const __attribute__((address_space(1))) void*)g,
        (__attribute__((address_space(3))) void*)l, 16, 0, 0);
}

// ---------------------------------------------------------------------------
// bf16 MFMA GEMM — r12 loop config + r16 z-aware L2 swizzle.
// r17: stage(t+2) issued FIRST after the barrier (before ds_reads) — vmem
// loads start their L2 latency ~200cy earlier; vmem/LDS issue ports are
// independent. Overwrite safety unchanged: buf (t+2)%3 == buf (t-1)%3,
// whose reads completed before barrier t in every wave's program order.
// ---------------------------------------------------------------------------
template<int EPI, int ACC, int OBF, int SPLIT>
__global__ __launch_bounds__(256) void gemm_bf16(
    const ushort_t* __restrict__ A, const ushort_t* __restrict__ Bt,
    const float* __restrict__ bias, void* __restrict__ Cout,
    int M, int N, int K)
{
    __shared__ __align__(16) short Abuf[3][128 * 32];
    __shared__ __align__(16) short Bbuf[3][128 * 32];

    const int tid  = threadIdx.x;
    const int lane = tid & 63, wid = tid >> 6;
    const int wr = wid >> 1, wc = wid & 1;

    // z-aware bijective XCD remap + 2D patch decode (r16)
    const int gx = gridDim.x, gy = gridDim.y;
    const int pp = gx * gy;
    const int T  = pp * gridDim.z;
    const int flatz = (blockIdx.z * gy + blockIdx.y) * gx + blockIdx.x;
    int bx, by, bz;
    if (T & 7) { bx = blockIdx.x; by = blockIdx.y; bz = blockIdx.z; }
    else {
        const int swz = (flatz & 7) * (T >> 3) + (flatz >> 3);
        bz = swz / pp;
        const int r  = swz % pp;
        const int GRP = (gy >= 8) ? 8 : 4;
        by = (r / (gx * GRP)) * GRP + (r % GRP);
        bx = (r / GRP) % gx;
    }
    const int row0 = by * 128, col0 = bx * 128;
    const int kb = (SPLIT > 1) ? bz * (K / SPLIT) : 0;
    const int klen = (SPLIT > 1) ? (K / SPLIT) : K;

    const int r0 = tid >> 2, s0 = tid & 3;
    const int lrow = lane & 15;
    const int lg = lane >> 4;
    const int rx = (lrow >> 1) & 3;

    f32x4 acc[4][4] = {};

    auto stage = [&](int buf, int t) {
        const int k0 = kb + (t << 5);
        #pragma unroll
        for (int i = 0; i < 2; ++i) {
            const int r = r0 + i * 64;
            const int ksl = (s0 ^ ((r >> 1) & 3)) * 8;
            gld_lds16(A  + (size_t)(row0 + r) * K + k0 + ksl,
                      &Abuf[buf][(tid + i * 256) * 8]);
            gld_lds16(Bt + (size_t)(col0 + r) * K + k0 + ksl,
                      &Bbuf[buf][(tid + i * 256) * 8]);
        }
    };

    const int nt = klen >> 5;
    stage(0, 0);
    stage(1, 1);

    for (int t = 0; t < nt; ++t) {
        const int ib = t % 3;
        // wait for buf[ib]'s 4 loads; keep later ones in flight
        if (t < nt - 1) { asm volatile("s_waitcnt vmcnt(4)" ::: "memory"); }
        else            { asm volatile("s_waitcnt vmcnt(0)" ::: "memory"); }
        __builtin_amdgcn_s_barrier();            // ib landed; all t-1 reads done
        __builtin_amdgcn_sched_barrier(0);       // nothing hoists above barrier

        if (t + 2 < nt) stage((t + 2) % 3, t + 2);   // r17: issue loads FIRST

        bf16x8 a[4], b[4];
        const int ts = (lg ^ rx) * 8;
        #pragma unroll
        for (int m = 0; m < 4; ++m)
            a[m] = *(const bf16x8*)&Abuf[ib][(wr * 64 + m * 16 + lrow) * 32 + ts];
        #pragma unroll
        for (int n = 0; n < 4; ++n)
            b[n] = *(const bf16x8*)&Bbuf[ib][(wc * 64 + n * 16 + lrow) * 32 + ts];

        asm volatile("s_waitcnt lgkmcnt(0)" ::: "memory");   // frags in regs

        #pragma unroll
        for (int m = 0; m < 4; ++m)
            #pragma unroll
            for (int n = 0; n < 4; ++n)
                acc[m][n] = __builtin_amdgcn_mfma_f32_16x16x32_bf16(
                    a[m], b[n], acc[m][n], 0, 0, 0);
    }

    const int rbase = lg * 4;
    #pragma unroll
    for (int n = 0; n < 4; ++n) {
        const int c = col0 + wc * 64 + n * 16 + lrow;
        const float bv = bias ? bias[c] : 0.f;
        #pragma unroll
        for (int m = 0; m < 4; ++m) {
            const int rb = row0 + wr * 64 + m * 16 + rbase;
            #pragma unroll
            for (int g = 0; g < 4; ++g) {
                const size_t idx = (size_t)(rb + g) * N + c;
                if (SPLIT > 1) {
                    float v = acc[m][n][g] + (bz == 0 ? bv : 0.f);
                    unsafeAtomicAdd(&((float*)Cout)[idx], v);
                } else {
                    float v = acc[m][n][g] + bv;
                    if (EPI == 1) v = v / (1.f + expf(-v));
                    if (EPI == 2) v = 0.5f * v * (1.f + erff(v * 0.70710678f));
                    if (OBF) {
                        ((ushort_t*)Cout)[idx] = f2bf(v);
                    } else {
                        float* Cf = (float*)Cout;
                        if (ACC) v += Cf[idx];
                        Cf[idx] = v;
                    }
                }
            }
        }
    }
}

// ---------------------------------------------------------------------------
// transpose + f32->bf16 cast (r15 vectorized)
// ---------------------------------------------------------------------------
__global__ __launch_bounds__(256) void transpose_cast(
    const float* __restrict__ in, ushort_t* __restrict__ out, int K, int N, int Kp)
{
    __shared__ float t[64][65];
    const int n0 = blockIdx.x * 64, k0 = blockIdx.y * 64;
    const int tid = threadIdx.x;
    const int kr = tid >> 4, nc = (tid & 15) * 4;
    #pragma unroll
    for (int j = 0; j < 4; ++j) {
        const int k = k0 + kr + j * 16;
        f32x4 v = {0.f, 0.f, 0.f, 0.f};
        if (k < K) v = *(const f32x4*)&in[(size_t)k * N + n0 + nc];
        *(f32x4*)&t[kr + j * 16][nc] = v;
    }
    __syncthreads();
    const int n = tid >> 3, kg = (tid & 7) * 8;
    #pragma unroll
    for (int j = 0; j < 2; ++j) {
        const int nn = n + j * 32;
        bf16x8 v;
        #pragma unroll
        for (int e = 0; e < 8; ++e)
            v[e] = (short)f2bf(t[kg + e][nn]);
        *(bf16x8*)&out[(size_t)(n0 + nn) * Kp + k0 + kg] = v;
    }
}

__global__ __launch_bounds__(256) void cast_hs(
    const float* __restrict__ in, ushort_t* __restrict__ out)
{
    int idx = blockIdx.x * 256 + threadIdx.x;
    if (idx >= SEQ * PATCH_KP) return;
    int s = idx / PATCH_KP, k = idx % PATCH_KP;
    out[idx] = (k < PATCH_IN) ? f2bf(in[(size_t)s * PATCH_IN + k]) : 0;
}

// gelu epilogue for split-K mrg1
__global__ __launch_bounds__(256) void gelu_cast(
    const float* __restrict__ in, ushort_t* __restrict__ out)
{
    const int idx = blockIdx.x * 256 + threadIdx.x;
    f32x4 v = ((const f32x4*)in)[idx];
    s16x4 r;
    #pragma unroll
    for (int j = 0; j < 4; ++j)
        r[j] = (short)f2bf(0.5f * v[j] * (1.f + erff(v[j] * 0.70710678f)));
    *(s16x4*)&out[idx * 4] = r;
}

// ---------------------------------------------------------------------------
// LayerNorm (unchanged)
// ---------------------------------------------------------------------------
__global__ __launch_bounds__(256) void ln_f32(
    const float* __restrict__ x, const float* __restrict__ w,
    const float* __restrict__ b, ushort_t* __restrict__ y, int D)
{
    const int row = blockIdx.x;
    const float* xr = x + (size_t)row * D;
    float s = 0.f, ss = 0.f;
    for (int d = threadIdx.x; d < D; d += 256) {
        float v = xr[d];
        s += v; ss = fmaf(v, v, ss);
    }
    __shared__ float red[2][4];
    const int lane = threadIdx.x & 63, wid = threadIdx.x >> 6;
    #pragma unroll
    for (int off = 32; off; off >>= 1) {
        s  += __shfl_xor(s,  off);
        ss += __shfl_xor(ss, off);
    }
    if (lane == 0) { red[0][wid] = s; red[1][wid] = ss; }
    __syncthreads();
    s  = red[0][0] + red[0][1] + red[0][2] + red[0][3];
    ss = red[1][0] + red[1][1] + red[1][2] + red[1][3];
    const float mu  = s / D;
    const float var = ss / D - mu * mu;
    const float inv = rsqrtf(var + 1e-6f);
    ushort_t* yr = y + (size_t)row * D;
    for (int d = threadIdx.x; d < D; d += 256)
        yr[d] = f2bf((xr[d] - mu) * inv * w[d] + b[d]);
}

// ---------------------------------------------------------------------------
// RoPE + scale + head-major relayout (bf16 in)
// ---------------------------------------------------------------------------
__global__ __launch_bounds__(256) void rope_cast_qk(
    const ushort_t* __restrict__ qkv, const int* __restrict__ pos,
    ushort_t* __restrict__ qb, ushort_t* __restrict__ kb)
{
    int idx = blockIdx.x * 256 + threadIdx.x;
    const int j = idx % 48;
    const int h = (idx / 48) % HEADS;
    const int s = idx / (48 * HEADS);
    if (s >= SEQ) return;
    const size_t ob = ((size_t)h * SEQ + s) * 96;
    if (j >= 40) {
        qb[ob + 40 + j] = 0; qb[ob + 48 + j] = 0;
        kb[ob + 40 + j] = 0; kb[ob + 48 + j] = 0;
        return;
    }
    const float p = (float)pos[s * 2 + (j / 20)];
    const float f = p * powf(10000.f, -(float)(j % 20) / 20.f);
    float c, sn;
    sincosf(f, &c, &sn);
    const ushort_t* q = qkv + (size_t)s * QKVN + h * HD;
    const ushort_t* k = q + EMBED;
    const float scale = 0.11180339887498949f;
    float q1 = bf2f(q[j]), q2 = bf2f(q[j + 40]);
    qb[ob + j]      = f2bf((q1 * c - q2 * sn) * scale);
    qb[ob + j + 40] = f2bf((q2 * c + q1 * sn) * scale);
    float k1 = bf2f(k[j]), k2 = bf2f(k[j + 40]);
    kb[ob + j]      = f2bf(k1 * c - k2 * sn);
    kb[ob + j + 40] = f2bf(k2 * c + k1 * sn);
}

// ---------------------------------------------------------------------------
// V transpose, LDS-tiled, bf16 copy-through
// ---------------------------------------------------------------------------
__global__ __launch_bounds__(320) void v_transpose(
    const ushort_t* __restrict__ qkv, ushort_t* __restrict__ vtb)
{
    __shared__ ushort_t t[32][81];
    const int sb = blockIdx.x * 32, h = blockIdx.y;
    const int tx = threadIdx.x, ty = threadIdx.y;      // 80 x 4
    #pragma unroll
    for (int i = 0; i < 8; ++i) {
        const int s = ty * 8 + i;
        t[s][tx] = qkv[(size_t)(sb + s) * QKVN + 2 * EMBED + h * HD + tx];
    }
    __syncthreads();
    const int tid = ty * 80 + tx;
    const int d = tid >> 2, s0 = (tid & 3) * 8;
    bf16x8 v;
    #pragma unroll
    for (int j = 0; j < 8; ++j)
        v[j] = (short)t[s0 + j][d];
    *(bf16x8*)&vtb[((size_t)h * 80 + d) * SEQ + sb + s0] = v;
}

// ---------------------------------------------------------------------------
// MFMA flash attention (unchanged)
// ---------------------------------------------------------------------------
#define AKC  64
#define KSTR 104
#define VSTR 72
#define PSTR 72

__global__ __launch_bounds__(256) void attn_mfma(
    const ushort_t* __restrict__ qb, const ushort_t* __restrict__ kb,
    const ushort_t* __restrict__ vtb, ushort_t* __restrict__ out)
{
    const int hh = blockIdx.x;
    const int seg = blockIdx.y;
    const int tid = threadIdx.x, lane = tid & 63, wid = tid >> 6;
    const int lr = lane & 15, lg = lane >> 4;

    __shared__ __align__(16) short Ks[AKC * KSTR];
    __shared__ __align__(16) short Vs[80 * VSTR];
    __shared__ __align__(16) short Ps[4][16 * PSTR];

    const int sq = seg * SEGLEN;
    const int qrow0 = sq + blockIdx.z * 64 + wid * 16;

    bf16x8 qf[3];
    #pragma unroll
    for (int f = 0; f < 3; ++f)
        qf[f] = *(const bf16x8*)&qb[((size_t)hh * SEQ + qrow0 + lr) * 96 + f * 32 + lg * 8];

    f32x4 o[5] = {};
    float m[4], l[4];
    #pragma unroll
    for (int g = 0; g < 4; ++g) { m[g] = -1e30f; l[g] = 0.f; }

    for (int c0 = 0; c0 < SEGLEN; c0 += AKC) {
        __syncthreads();
        #pragma unroll
        for (int i = 0; i < 3; ++i) {
            int id = tid + i * 256;
            int r = id / 12, s = id % 12;
            *(bf16x8*)&Ks[r * KSTR + s * 8] =
                *(const bf16x8*)&kb[((size_t)hh * SEQ + sq + c0 + r) * 96 + s * 8];
        }
        #pragma unroll
        for (int i = 0; i < 3; ++i) {
            int id = tid + i * 256;
            if (id < 640) {
                int d = id / 8, s = id % 8;
                *(bf16x8*)&Vs[d * VSTR + s * 8] =
                    *(const bf16x8*)&vtb[((size_t)hh * 80 + d) * SEQ + sq + c0 + s * 8];
            }
        }
        __syncthreads();

        f32x4 sc[4] = {};
        #pragma unroll
        for (int kt = 0; kt < 4; ++kt)
            #pragma unroll
            for (int f = 0; f < 3; ++f) {
                bf16x8 kf = *(const bf16x8*)&Ks[(kt * 16 + lr) * KSTR + f * 32 + lg * 8];
                sc[kt] = __builtin_amdgcn_mfma_f32_16x16x32_bf16(qf[f], kf, sc[kt], 0, 0, 0);
            }

        float corr[4], ps[4];
        #pragma unroll
        for (int g = 0; g < 4; ++g) {
            float v = fmaxf(fmaxf(sc[0][g], sc[1][g]), fmaxf(sc[2][g], sc[3][g]));
            v = fmaxf(v, __shfl_xor(v, 1));
            v = fmaxf(v, __shfl_xor(v, 2));
            v = fmaxf(v, __shfl_xor(v, 4));
            v = fmaxf(v, __shfl_xor(v, 8));
            const float mn = fmaxf(m[g], v);
            corr[g] = __expf(m[g] - mn);
            m[g] = mn;
            ps[g] = 0.f;
        }
        #pragma unroll
        for (int kt = 0; kt < 4; ++kt)
            #pragma unroll
            for (int g = 0; g < 4; ++g) {
                float p = __expf(sc[kt][g] - m[g]);
                ps[g] += p;
                Ps[wid][(lg * 4 + g) * PSTR + kt * 16 + lr] = f2bf(p);
            }
        #pragma unroll
        for (int g = 0; g < 4; ++g) {
            float rs = ps[g];
            rs += __shfl_xor(rs, 1);
            rs += __shfl_xor(rs, 2);
            rs += __shfl_xor(rs, 4);
            rs += __shfl_xor(rs, 8);
            l[g] = l[g] * corr[g] + rs;
        }
        #pragma unroll
        for (int n = 0; n < 5; ++n)
            #pragma unroll
            for (int g = 0; g < 4; ++g) o[n][g] *= corr[g];

        #pragma unroll
        for (int jf = 0; jf < 2; ++jf) {
            bf16x8 pa = *(const bf16x8*)&Ps[wid][lr * PSTR + jf * 32 + lg * 8];
            #pragma unroll
            for (int n = 0; n < 5; ++n) {
                bf16x8 vf = *(const bf16x8*)&Vs[(n * 16 + lr) * VSTR + jf * 32 + lg * 8];
                o[n] = __builtin_amdgcn_mfma_f32_16x16x32_bf16(pa, vf, o[n], 0, 0, 0);
            }
        }
    }

    #pragma unroll
    for (int g = 0; g < 4; ++g) {
        const float inv = 1.f / l[g];
        const int r = qrow0 + lg * 4 + g;
        #pragma unroll
        for (int n = 0; n < 5; ++n)
            out[(size_t)r * EMBED + hh * HD + n * 16 + lr] = f2bf(o[n][g] * inv);
    }
}

// ---------------------------------------------------------------------------

extern "C" void kernel_launch(void* const* d_in, const int* in_sizes, int n_in,
                              void* d_out, int out_size, void* d_ws, size_t ws_size,
                              hipStream_t stream)
{
    const float* hs      = (const float*)d_in[0];
    const int*   pos     = (const int*)  d_in[1];
    const float* patch_w = (const float*)d_in[3];
    const float* ln1_w   = (const float*)d_in[4];
    const float* ln1_b   = (const float*)d_in[5];
    const float* ln2_w   = (const float*)d_in[6];
    const float* ln2_b   = (const float*)d_in[7];
    const float* qkv_w   = (const float*)d_in[8];
    const float* qkv_b   = (const float*)d_in[9];
    const float* proj_w  = (const float*)d_in[10];
    const float* proj_b  = (const float*)d_in[11];
    const float* fc1_w   = (const float*)d_in[12];
    const float* fc1_b   = (const float*)d_in[13];
    const float* fc2_w   = (const float*)d_in[14];
    const float* fc2_b   = (const float*)d_in[15];
    const float* mln_w   = (const float*)d_in[16];
    const float* mln_b   = (const float*)d_in[17];
    const float* w1      = (const float*)d_in[18];
    const float* b1      = (const float*)d_in[19];
    const float* w2      = (const float*)d_in[20];
    const float* b2      = (const float*)d_in[21];
    float* out = (float*)d_out;

    char* p = (char*)d_ws;
    float*    x      = (float*)p;            p += (size_t)SEQ * EMBED * 4;
    float*    qkvbuf = (float*)p;            p += (size_t)SEQ * QKVN * 4;
    ushort_t* hbf    = (ushort_t*)p;         p += (size_t)SEQ * EMBED * 2;
    ushort_t* hsbf   = (ushort_t*)p;         p += (size_t)SEQ * PATCH_KP * 2;
    ushort_t* wbuf   = (ushort_t*)p;
    ushort_t* qkvbf  = (ushort_t*)qkvbuf;
    ushort_t* fc1out = (ushort_t*)qkvbuf;
    float*    mrg1f  = (float*)((char*)qkvbuf + (8 << 20));
    ushort_t* qbv = wbuf;
    ushort_t* kbv = qbv + (size_t)HEADS * SEQ * 96;
    ushort_t* vtb = kbv + (size_t)HEADS * SEQ * 96;

    auto tgrid = [](int N, int Kp) { return dim3(N / 64, Kp / 64); };
    auto ggrid = [](int M, int N, int S = 1) { return dim3(N / 128, M / 128, S); };

    cast_hs<<<(SEQ * PATCH_KP + 255) / 256, 256, 0, stream>>>(hs, hsbf);
    transpose_cast<<<tgrid(EMBED, PATCH_KP), 256, 0, stream>>>(
        patch_w, wbuf, PATCH_IN, EMBED, PATCH_KP);
    hipMemsetAsync(x, 0, (size_t)SEQ * EMBED * 4, stream);
    gemm_bf16<0, 0, 0, 2><<<ggrid(SEQ, EMBED, 2), 256, 0, stream>>>(
        hsbf, wbuf, nullptr, x, SEQ, EMBED, PATCH_KP);

    for (int i = 0; i < 2; ++i) {
        ln_f32<<<SEQ, 256, 0, stream>>>(x, ln1_w + i * EMBED, ln1_b + i * EMBED, hbf, EMBED);
        transpose_cast<<<tgrid(QKVN, EMBED), 256, 0, stream>>>(
            qkv_w + (size_t)i * EMBED * QKVN, wbuf, EMBED, QKVN, EMBED);
        gemm_bf16<0, 0, 1, 1><<<ggrid(SEQ, QKVN), 256, 0, stream>>>(
            hbf, wbuf, qkv_b + i * QKVN, qkvbf, SEQ, QKVN, EMBED);
        rope_cast_qk<<<SEQ * HEADS * 48 / 256, 256, 0, stream>>>(qkvbf, pos, qbv, kbv);
        v_transpose<<<dim3(SEQ / 32, HEADS), dim3(80, 4), 0, stream>>>(qkvbf, vtb);
        attn_mfma<<<dim3(HEADS, NSEG, SEGLEN / 64), 256, 0, stream>>>(qbv, kbv, vtb, hbf);
        transpose_cast<<<tgrid(EMBED, EMBED), 256, 0, stream>>>(
            proj_w + (size_t)i * EMBED * EMBED, wbuf, EMBED, EMBED, EMBED);
        gemm_bf16<0, 1, 0, 2><<<ggrid(SEQ, EMBED, 2), 256, 0, stream>>>(
            hbf, wbuf, proj_b + i * EMBED, x, SEQ, EMBED, EMBED);
        ln_f32<<<SEQ, 256, 0, stream>>>(x, ln2_w + i * EMBED, ln2_b + i * EMBED, hbf, EMBED);
        transpose_cast<<<tgrid(MLP, EMBED), 256, 0, stream>>>(
            fc1_w + (size_t)i * EMBED * MLP, wbuf, EMBED, MLP, EMBED);
        gemm_bf16<1, 0, 1, 1><<<ggrid(SEQ, MLP), 256, 0, stream>>>(
            hbf, wbuf, fc1_b + i * MLP, fc1out, SEQ, MLP, EMBED);
        transpose_cast<<<tgrid(EMBED, MLP), 256, 0, stream>>>(
            fc2_w + (size_t)i * MLP * EMBED, wbuf, MLP, EMBED, MLP);
        gemm_bf16<0, 1, 0, 4><<<ggrid(SEQ, EMBED, 4), 256, 0, stream>>>(
            fc1out, wbuf, fc2_b + i * EMBED, x, SEQ, EMBED, MLP);
    }

    // merger
    ln_f32<<<SEQ, 256, 0, stream>>>(x, mln_w, mln_b, hbf, EMBED);
    transpose_cast<<<tgrid(HIDDEN, 4 * EMBED), 256, 0, stream>>>(
        w1, wbuf, 4 * EMBED, HIDDEN, 4 * EMBED);
    hipMemsetAsync(mrg1f, 0, (size_t)MROWS * HIDDEN * 4, stream);
    gemm_bf16<0, 0, 0, 4><<<ggrid(MROWS, HIDDEN, 4), 256, 0, stream>>>(
        hbf, wbuf, b1, mrg1f, MROWS, HIDDEN, 4 * EMBED);
    gelu_cast<<<MROWS * HIDDEN / 1024, 256, 0, stream>>>(mrg1f, fc1out);
    transpose_cast<<<tgrid(HIDDEN, HIDDEN), 256, 0, stream>>>(
        w2, wbuf, HIDDEN, HIDDEN, HIDDEN);
    hipMemsetAsync(out, 0, (size_t)MROWS * HIDDEN * 4, stream);
    gemm_bf16<0, 0, 0, 4><<<ggrid(MROWS, HIDDEN, 4), 256, 0, stream>>>(
        fc1out, wbuf, b2, out, MROWS, HIDDEN, HIDDEN);
}

// Round 18
// 703.605 us; speedup vs baseline: 1.0651x; 1.0651x over previous
//
#include <hip/hip_runtime.h>
#include <math.h>

#define SEQ    2048
#define EMBED  1280
#define HEADS  16
#define HD     80
#define MLP    5120
#define HIDDEN 3584
#define QKVN   3840
#define SEGLEN 1024
#define NSEG   2
#define PATCH_IN 1176
#define PATCH_KP 1280   // mult of 128
#define MROWS  512

typedef __attribute__((ext_vector_type(8))) short bf16x8;
typedef __attribute__((ext_vector_type(4))) short s16x4;
typedef __attribute__((ext_vector_type(4))) float f32x4;
typedef unsigned short ushort_t;

__device__ __forceinline__ ushort_t f2bf(float f) {
    unsigned u = __builtin_bit_cast(unsigned, f);
    unsigned r = u + 0x7FFFu + ((u >> 16) & 1u);   // RNE
    return (ushort_t)(r >> 16);
}

__device__ __forceinline__ float bf2f(ushort_t h) {
    unsigned u = (unsigned)h << 16;
    return __builtin_bit_cast(float, u);
}

__device__ __forceinline__ void gld_lds16(const void* g, void* l) {
    __builtin_amdgcn_global_load_lds(
        (const __attribute__((address_space(1))) void*)g,
        (__attribute__((address_space(3))) void*)l, 16, 0, 0);
}

// ---------------------------------------------------------------------------
// bf16 MFMA GEMM — r16 configuration EXACTLY (r17's stage-first reorder
// regressed 6%: in-order issue put 4 vmem issues ahead of ds_reads, delaying
// the lgkmcnt-gated MFMAs every step; ds_reads-first lets the stage issue
// hide under ds_read latency instead). r12 loop + r16 z-aware L2 swizzle.
// ---------------------------------------------------------------------------
template<int EPI, int ACC, int OBF, int SPLIT>
__global__ __launch_bounds__(256) void gemm_bf16(
    const ushort_t* __restrict__ A, const ushort_t* __restrict__ Bt,
    const float* __restrict__ bias, void* __restrict__ Cout,
    int M, int N, int K)
{
    __shared__ __align__(16) short Abuf[3][128 * 32];
    __shared__ __align__(16) short Bbuf[3][128 * 32];

    const int tid  = threadIdx.x;
    const int lane = tid & 63, wid = tid >> 6;
    const int wr = wid >> 1, wc = wid & 1;

    // z-aware bijective XCD remap + 2D patch decode (r16)
    const int gx = gridDim.x, gy = gridDim.y;
    const int pp = gx * gy;
    const int T  = pp * gridDim.z;
    const int flatz = (blockIdx.z * gy + blockIdx.y) * gx + blockIdx.x;
    int bx, by, bz;
    if (T & 7) { bx = blockIdx.x; by = blockIdx.y; bz = blockIdx.z; }
    else {
        const int swz = (flatz & 7) * (T >> 3) + (flatz >> 3);
        bz = swz / pp;
        const int r  = swz % pp;
        const int GRP = (gy >= 8) ? 8 : 4;
        by = (r / (gx * GRP)) * GRP + (r % GRP);
        bx = (r / GRP) % gx;
    }
    const int row0 = by * 128, col0 = bx * 128;
    const int kb = (SPLIT > 1) ? bz * (K / SPLIT) : 0;
    const int klen = (SPLIT > 1) ? (K / SPLIT) : K;

    const int r0 = tid >> 2, s0 = tid & 3;
    const int lrow = lane & 15;
    const int lg = lane >> 4;
    const int rx = (lrow >> 1) & 3;

    f32x4 acc[4][4] = {};

    auto stage = [&](int buf, int t) {
        const int k0 = kb + (t << 5);
        #pragma unroll
        for (int i = 0; i < 2; ++i) {
            const int r = r0 + i * 64;
            const int ksl = (s0 ^ ((r >> 1) & 3)) * 8;
            gld_lds16(A  + (size_t)(row0 + r) * K + k0 + ksl,
                      &Abuf[buf][(tid + i * 256) * 8]);
            gld_lds16(Bt + (size_t)(col0 + r) * K + k0 + ksl,
                      &Bbuf[buf][(tid + i * 256) * 8]);
        }
    };

    const int nt = klen >> 5;
    stage(0, 0);
    stage(1, 1);

    for (int t = 0; t < nt; ++t) {
        const int ib = t % 3;
        if (t < nt - 1) { asm volatile("s_waitcnt vmcnt(4)" ::: "memory"); }
        else            { asm volatile("s_waitcnt vmcnt(0)" ::: "memory"); }
        __builtin_amdgcn_s_barrier();
        __builtin_amdgcn_sched_barrier(0);

        bf16x8 a[4], b[4];
        const int ts = (lg ^ rx) * 8;
        #pragma unroll
        for (int m = 0; m < 4; ++m)
            a[m] = *(const bf16x8*)&Abuf[ib][(wr * 64 + m * 16 + lrow) * 32 + ts];
        #pragma unroll
        for (int n = 0; n < 4; ++n)
            b[n] = *(const bf16x8*)&Bbuf[ib][(wc * 64 + n * 16 + lrow) * 32 + ts];

        if (t + 2 < nt) stage((t + 2) % 3, t + 2);

        asm volatile("s_waitcnt lgkmcnt(0)" ::: "memory");

        #pragma unroll
        for (int m = 0; m < 4; ++m)
            #pragma unroll
            for (int n = 0; n < 4; ++n)
                acc[m][n] = __builtin_amdgcn_mfma_f32_16x16x32_bf16(
                    a[m], b[n], acc[m][n], 0, 0, 0);
    }

    const int rbase = lg * 4;
    #pragma unroll
    for (int n = 0; n < 4; ++n) {
        const int c = col0 + wc * 64 + n * 16 + lrow;
        const float bv = bias ? bias[c] : 0.f;
        #pragma unroll
        for (int m = 0; m < 4; ++m) {
            const int rb = row0 + wr * 64 + m * 16 + rbase;
            #pragma unroll
            for (int g = 0; g < 4; ++g) {
                const size_t idx = (size_t)(rb + g) * N + c;
                if (SPLIT > 1) {
                    float v = acc[m][n][g] + (bz == 0 ? bv : 0.f);
                    unsafeAtomicAdd(&((float*)Cout)[idx], v);
                } else {
                    float v = acc[m][n][g] + bv;
                    if (EPI == 1) v = v / (1.f + expf(-v));
                    if (EPI == 2) v = 0.5f * v * (1.f + erff(v * 0.70710678f));
                    if (OBF) {
                        ((ushort_t*)Cout)[idx] = f2bf(v);
                    } else {
                        float* Cf = (float*)Cout;
                        if (ACC) v += Cf[idx];
                        Cf[idx] = v;
                    }
                }
            }
        }
    }
}

// ---------------------------------------------------------------------------
// transpose + f32->bf16 cast (r15 vectorized)
// ---------------------------------------------------------------------------
__global__ __launch_bounds__(256) void transpose_cast(
    const float* __restrict__ in, ushort_t* __restrict__ out, int K, int N, int Kp)
{
    __shared__ float t[64][65];
    const int n0 = blockIdx.x * 64, k0 = blockIdx.y * 64;
    const int tid = threadIdx.x;
    const int kr = tid >> 4, nc = (tid & 15) * 4;
    #pragma unroll
    for (int j = 0; j < 4; ++j) {
        const int k = k0 + kr + j * 16;
        f32x4 v = {0.f, 0.f, 0.f, 0.f};
        if (k < K) v = *(const f32x4*)&in[(size_t)k * N + n0 + nc];
        *(f32x4*)&t[kr + j * 16][nc] = v;
    }
    __syncthreads();
    const int n = tid >> 3, kg = (tid & 7) * 8;
    #pragma unroll
    for (int j = 0; j < 2; ++j) {
        const int nn = n + j * 32;
        bf16x8 v;
        #pragma unroll
        for (int e = 0; e < 8; ++e)
            v[e] = (short)f2bf(t[kg + e][nn]);
        *(bf16x8*)&out[(size_t)(n0 + nn) * Kp + k0 + kg] = v;
    }
}

__global__ __launch_bounds__(256) void cast_hs(
    const float* __restrict__ in, ushort_t* __restrict__ out)
{
    int idx = blockIdx.x * 256 + threadIdx.x;
    if (idx >= SEQ * PATCH_KP) return;
    int s = idx / PATCH_KP, k = idx % PATCH_KP;
    out[idx] = (k < PATCH_IN) ? f2bf(in[(size_t)s * PATCH_IN + k]) : 0;
}

// gelu epilogue for split-K mrg1
__global__ __launch_bounds__(256) void gelu_cast(
    const float* __restrict__ in, ushort_t* __restrict__ out)
{
    const int idx = blockIdx.x * 256 + threadIdx.x;
    f32x4 v = ((const f32x4*)in)[idx];
    s16x4 r;
    #pragma unroll
    for (int j = 0; j < 4; ++j)
        r[j] = (short)f2bf(0.5f * v[j] * (1.f + erff(v[j] * 0.70710678f)));
    *(s16x4*)&out[idx * 4] = r;
}

// ---------------------------------------------------------------------------
// LayerNorm
// ---------------------------------------------------------------------------
__global__ __launch_bounds__(256) void ln_f32(
    const float* __restrict__ x, const float* __restrict__ w,
    const float* __restrict__ b, ushort_t* __restrict__ y, int D)
{
    const int row = blockIdx.x;
    const float* xr = x + (size_t)row * D;
    float s = 0.f, ss = 0.f;
    for (int d = threadIdx.x; d < D; d += 256) {
        float v = xr[d];
        s += v; ss = fmaf(v, v, ss);
    }
    __shared__ float red[2][4];
    const int lane = threadIdx.x & 63, wid = threadIdx.x >> 6;
    #pragma unroll
    for (int off = 32; off; off >>= 1) {
        s  += __shfl_xor(s,  off);
        ss += __shfl_xor(ss, off);
    }
    if (lane == 0) { red[0][wid] = s; red[1][wid] = ss; }
    __syncthreads();
    s  = red[0][0] + red[0][1] + red[0][2] + red[0][3];
    ss = red[1][0] + red[1][1] + red[1][2] + red[1][3];
    const float mu  = s / D;
    const float var = ss / D - mu * mu;
    const float inv = rsqrtf(var + 1e-6f);
    ushort_t* yr = y + (size_t)row * D;
    for (int d = threadIdx.x; d < D; d += 256)
        yr[d] = f2bf((xr[d] - mu) * inv * w[d] + b[d]);
}

// ---------------------------------------------------------------------------
// RoPE + scale + head-major relayout (bf16 in)
// ---------------------------------------------------------------------------
__global__ __launch_bounds__(256) void rope_cast_qk(
    const ushort_t* __restrict__ qkv, const int* __restrict__ pos,
    ushort_t* __restrict__ qb, ushort_t* __restrict__ kb)
{
    int idx = blockIdx.x * 256 + threadIdx.x;
    const int j = idx % 48;
    const int h = (idx / 48) % HEADS;
    const int s = idx / (48 * HEADS);
    if (s >= SEQ) return;
    const size_t ob = ((size_t)h * SEQ + s) * 96;
    if (j >= 40) {
        qb[ob + 40 + j] = 0; qb[ob + 48 + j] = 0;
        kb[ob + 40 + j] = 0; kb[ob + 48 + j] = 0;
        return;
    }
    const float p = (float)pos[s * 2 + (j / 20)];
    const float f = p * powf(10000.f, -(float)(j % 20) / 20.f);
    float c, sn;
    sincosf(f, &c, &sn);
    const ushort_t* q = qkv + (size_t)s * QKVN + h * HD;
    const ushort_t* k = q + EMBED;
    const float scale = 0.11180339887498949f;
    float q1 = bf2f(q[j]), q2 = bf2f(q[j + 40]);
    qb[ob + j]      = f2bf((q1 * c - q2 * sn) * scale);
    qb[ob + j + 40] = f2bf((q2 * c + q1 * sn) * scale);
    float k1 = bf2f(k[j]), k2 = bf2f(k[j + 40]);
    kb[ob + j]      = f2bf(k1 * c - k2 * sn);
    kb[ob + j + 40] = f2bf(k2 * c + k1 * sn);
}

// ---------------------------------------------------------------------------
// V transpose, LDS-tiled, bf16 copy-through
// ---------------------------------------------------------------------------
__global__ __launch_bounds__(320) void v_transpose(
    const ushort_t* __restrict__ qkv, ushort_t* __restrict__ vtb)
{
    __shared__ ushort_t t[32][81];
    const int sb = blockIdx.x * 32, h = blockIdx.y;
    const int tx = threadIdx.x, ty = threadIdx.y;      // 80 x 4
    #pragma unroll
    for (int i = 0; i < 8; ++i) {
        const int s = ty * 8 + i;
        t[s][tx] = qkv[(size_t)(sb + s) * QKVN + 2 * EMBED + h * HD + tx];
    }
    __syncthreads();
    const int tid = ty * 80 + tx;
    const int d = tid >> 2, s0 = (tid & 3) * 8;
    bf16x8 v;
    #pragma unroll
    for (int j = 0; j < 8; ++j)
        v[j] = (short)t[s0 + j][d];
    *(bf16x8*)&vtb[((size_t)h * 80 + d) * SEQ + sb + s0] = v;
}

// ---------------------------------------------------------------------------
// MFMA flash attention
// ---------------------------------------------------------------------------
#define AKC  64
#define KSTR 104
#define VSTR 72
#define PSTR 72

__global__ __launch_bounds__(256) void attn_mfma(
    const ushort_t* __restrict__ qb, const ushort_t* __restrict__ kb,
    const ushort_t* __restrict__ vtb, ushort_t* __restrict__ out)
{
    const int hh = blockIdx.x;
    const int seg = blockIdx.y;
    const int tid = threadIdx.x, lane = tid & 63, wid = tid >> 6;
    const int lr = lane & 15, lg = lane >> 4;

    __shared__ __align__(16) short Ks[AKC * KSTR];
    __shared__ __align__(16) short Vs[80 * VSTR];
    __shared__ __align__(16) short Ps[4][16 * PSTR];

    const int sq = seg * SEGLEN;
    const int qrow0 = sq + blockIdx.z * 64 + wid * 16;

    bf16x8 qf[3];
    #pragma unroll
    for (int f = 0; f < 3; ++f)
        qf[f] = *(const bf16x8*)&qb[((size_t)hh * SEQ + qrow0 + lr) * 96 + f * 32 + lg * 8];

    f32x4 o[5] = {};
    float m[4], l[4];
    #pragma unroll
    for (int g = 0; g < 4; ++g) { m[g] = -1e30f; l[g] = 0.f; }

    for (int c0 = 0; c0 < SEGLEN; c0 += AKC) {
        __syncthreads();
        #pragma unroll
        for (int i = 0; i < 3; ++i) {
            int id = tid + i * 256;
            int r = id / 12, s = id % 12;
            *(bf16x8*)&Ks[r * KSTR + s * 8] =
                *(const bf16x8*)&kb[((size_t)hh * SEQ + sq + c0 + r) * 96 + s * 8];
        }
        #pragma unroll
        for (int i = 0; i < 3; ++i) {
            int id = tid + i * 256;
            if (id < 640) {
                int d = id / 8, s = id % 8;
                *(bf16x8*)&Vs[d * VSTR + s * 8] =
                    *(const bf16x8*)&vtb[((size_t)hh * 80 + d) * SEQ + sq + c0 + s * 8];
            }
        }
        __syncthreads();

        f32x4 sc[4] = {};
        #pragma unroll
        for (int kt = 0; kt < 4; ++kt)
            #pragma unroll
            for (int f = 0; f < 3; ++f) {
                bf16x8 kf = *(const bf16x8*)&Ks[(kt * 16 + lr) * KSTR + f * 32 + lg * 8];
                sc[kt] = __builtin_amdgcn_mfma_f32_16x16x32_bf16(qf[f], kf, sc[kt], 0, 0, 0);
            }

        float corr[4], ps[4];
        #pragma unroll
        for (int g = 0; g < 4; ++g) {
            float v = fmaxf(fmaxf(sc[0][g], sc[1][g]), fmaxf(sc[2][g], sc[3][g]));
            v = fmaxf(v, __shfl_xor(v, 1));
            v = fmaxf(v, __shfl_xor(v, 2));
            v = fmaxf(v, __shfl_xor(v, 4));
            v = fmaxf(v, __shfl_xor(v, 8));
            const float mn = fmaxf(m[g], v);
            corr[g] = __expf(m[g] - mn);
            m[g] = mn;
            ps[g] = 0.f;
        }
        #pragma unroll
        for (int kt = 0; kt < 4; ++kt)
            #pragma unroll
            for (int g = 0; g < 4; ++g) {
                float p = __expf(sc[kt][g] - m[g]);
                ps[g] += p;
                Ps[wid][(lg * 4 + g) * PSTR + kt * 16 + lr] = f2bf(p);
            }
        #pragma unroll
        for (int g = 0; g < 4; ++g) {
            float rs = ps[g];
            rs += __shfl_xor(rs, 1);
            rs += __shfl_xor(rs, 2);
            rs += __shfl_xor(rs, 4);
            rs += __shfl_xor(rs, 8);
            l[g] = l[g] * corr[g] + rs;
        }
        #pragma unroll
        for (int n = 0; n < 5; ++n)
            #pragma unroll
            for (int g = 0; g < 4; ++g) o[n][g] *= corr[g];

        #pragma unroll
        for (int jf = 0; jf < 2; ++jf) {
            bf16x8 pa = *(const bf16x8*)&Ps[wid][lr * PSTR + jf * 32 + lg * 8];
            #pragma unroll
            for (int n = 0; n < 5; ++n) {
                bf16x8 vf = *(const bf16x8*)&Vs[(n * 16 + lr) * VSTR + jf * 32 + lg * 8];
                o[n] = __builtin_amdgcn_mfma_f32_16x16x32_bf16(pa, vf, o[n], 0, 0, 0);
            }
        }
    }

    #pragma unroll
    for (int g = 0; g < 4; ++g) {
        const float inv = 1.f / l[g];
        const int r = qrow0 + lg * 4 + g;
        #pragma unroll
        for (int n = 0; n < 5; ++n)
            out[(size_t)r * EMBED + hh * HD + n * 16 + lr] = f2bf(o[n][g] * inv);
    }
}

// ---------------------------------------------------------------------------

extern "C" void kernel_launch(void* const* d_in, const int* in_sizes, int n_in,
                              void* d_out, int out_size, void* d_ws, size_t ws_size,
                              hipStream_t stream)
{
    const float* hs      = (const float*)d_in[0];
    const int*   pos     = (const int*)  d_in[1];
    const float* patch_w = (const float*)d_in[3];
    const float* ln1_w   = (const float*)d_in[4];
    const float* ln1_b   = (const float*)d_in[5];
    const float* ln2_w   = (const float*)d_in[6];
    const float* ln2_b   = (const float*)d_in[7];
    const float* qkv_w   = (const float*)d_in[8];
    const float* qkv_b   = (const float*)d_in[9];
    const float* proj_w  = (const float*)d_in[10];
    const float* proj_b  = (const float*)d_in[11];
    const float* fc1_w   = (const float*)d_in[12];
    const float* fc1_b   = (const float*)d_in[13];
    const float* fc2_w   = (const float*)d_in[14];
    const float* fc2_b   = (const float*)d_in[15];
    const float* mln_w   = (const float*)d_in[16];
    const float* mln_b   = (const float*)d_in[17];
    const float* w1      = (const float*)d_in[18];
    const float* b1      = (const float*)d_in[19];
    const float* w2      = (const float*)d_in[20];
    const float* b2      = (const float*)d_in[21];
    float* out = (float*)d_out;

    char* p = (char*)d_ws;
    float*    x      = (float*)p;            p += (size_t)SEQ * EMBED * 4;
    float*    qkvbuf = (float*)p;            p += (size_t)SEQ * QKVN * 4;
    ushort_t* hbf    = (ushort_t*)p;         p += (size_t)SEQ * EMBED * 2;
    ushort_t* hsbf   = (ushort_t*)p;         p += (size_t)SEQ * PATCH_KP * 2;
    ushort_t* wbuf   = (ushort_t*)p;
    ushort_t* qkvbf  = (ushort_t*)qkvbuf;
    ushort_t* fc1out = (ushort_t*)qkvbuf;
    float*    mrg1f  = (float*)((char*)qkvbuf + (8 << 20));
    ushort_t* qbv = wbuf;
    ushort_t* kbv = qbv + (size_t)HEADS * SEQ * 96;
    ushort_t* vtb = kbv + (size_t)HEADS * SEQ * 96;

    auto tgrid = [](int N, int Kp) { return dim3(N / 64, Kp / 64); };
    auto ggrid = [](int M, int N, int S = 1) { return dim3(N / 128, M / 128, S); };

    cast_hs<<<(SEQ * PATCH_KP + 255) / 256, 256, 0, stream>>>(hs, hsbf);
    transpose_cast<<<tgrid(EMBED, PATCH_KP), 256, 0, stream>>>(
        patch_w, wbuf, PATCH_IN, EMBED, PATCH_KP);
    hipMemsetAsync(x, 0, (size_t)SEQ * EMBED * 4, stream);
    gemm_bf16<0, 0, 0, 2><<<ggrid(SEQ, EMBED, 2), 256, 0, stream>>>(
        hsbf, wbuf, nullptr, x, SEQ, EMBED, PATCH_KP);

    for (int i = 0; i < 2; ++i) {
        ln_f32<<<SEQ, 256, 0, stream>>>(x, ln1_w + i * EMBED, ln1_b + i * EMBED, hbf, EMBED);
        transpose_cast<<<tgrid(QKVN, EMBED), 256, 0, stream>>>(
            qkv_w + (size_t)i * EMBED * QKVN, wbuf, EMBED, QKVN, EMBED);
        gemm_bf16<0, 0, 1, 1><<<ggrid(SEQ, QKVN), 256, 0, stream>>>(
            hbf, wbuf, qkv_b + i * QKVN, qkvbf, SEQ, QKVN, EMBED);
        rope_cast_qk<<<SEQ * HEADS * 48 / 256, 256, 0, stream>>>(qkvbf, pos, qbv, kbv);
        v_transpose<<<dim3(SEQ / 32, HEADS), dim3(80, 4), 0, stream>>>(qkvbf, vtb);
        attn_mfma<<<dim3(HEADS, NSEG, SEGLEN / 64), 256, 0, stream>>>(qbv, kbv, vtb, hbf);
        transpose_cast<<<tgrid(EMBED, EMBED), 256, 0, stream>>>(
            proj_w + (size_t)i * EMBED * EMBED, wbuf, EMBED, EMBED, EMBED);
        gemm_bf16<0, 1, 0, 2><<<ggrid(SEQ, EMBED, 2), 256, 0, stream>>>(
            hbf, wbuf, proj_b + i * EMBED, x, SEQ, EMBED, EMBED);
        ln_f32<<<SEQ, 256, 0, stream>>>(x, ln2_w + i * EMBED, ln2_b + i * EMBED, hbf, EMBED);
        transpose_cast<<<tgrid(MLP, EMBED), 256, 0, stream>>>(
            fc1_w + (size_t)i * EMBED * MLP, wbuf, EMBED, MLP, EMBED);
        gemm_bf16<1, 0, 1, 1><<<ggrid(SEQ, MLP), 256, 0, stream>>>(
            hbf, wbuf, fc1_b + i * MLP, fc1out, SEQ, MLP, EMBED);
        transpose_cast<<<tgrid(EMBED, MLP), 256, 0, stream>>>(
            fc2_w + (size_t)i * MLP * EMBED, wbuf, MLP, EMBED, MLP);
        gemm_bf16<0, 1, 0, 4><<<ggrid(SEQ, EMBED, 4), 256, 0, stream>>>(
            fc1out, wbuf, fc2_b + i * EMBED, x, SEQ, EMBED, MLP);
    }

    // merger
    ln_f32<<<SEQ, 256, 0, stream>>>(x, mln_w, mln_b, hbf, EMBED);
    transpose_cast<<<tgrid(HIDDEN, 4 * EMBED), 256, 0, stream>>>(
        w1, wbuf, 4 * EMBED, HIDDEN, 4 * EMBED);
    hipMemsetAsync(mrg1f, 0, (size_t)MROWS * HIDDEN * 4, stream);
    gemm_bf16<0, 0, 0, 4><<<ggrid(MROWS, HIDDEN, 4), 256, 0, stream>>>(
        hbf, wbuf, b1, mrg1f, MROWS, HIDDEN, 4 * EMBED);
    gelu_cast<<<MROWS * HIDDEN / 1024, 256, 0, stream>>>(mrg1f, fc1out);
    transpose_cast<<<tgrid(HIDDEN, HIDDEN), 256, 0, stream>>>(
        w2, wbuf, HIDDEN, HIDDEN, HIDDEN);
    hipMemsetAsync(out, 0, (size_t)MROWS * HIDDEN * 4, stream);
    gemm_bf16<0, 0, 0, 4><<<ggrid(MROWS, HIDDEN, 4), 256, 0, stream>>>(
        fc1out, wbuf, b2, out, MROWS, HIDDEN, HIDDEN);
}